// Round 1
// baseline (216.620 us; speedup 1.0000x reference)
//
#include <hip/hip_runtime.h>

typedef __bf16 bf16x8 __attribute__((ext_vector_type(8)));
typedef float f32x4 __attribute__((ext_vector_type(4)));

#define B_  4096   // batch
#define IN_ 1024
#define H_  1024
#define KD  2048   // IN_ + H_
#define ND  4096   // 4 * H_ (gates interleaved: row n = 4*h + g)
#define NT  32     // K tiles of 64

__device__ __forceinline__ unsigned short f2bf(float f) {
    union { float f; unsigned u; } v; v.f = f;
    unsigned r = v.u + 0x7FFFu + ((v.u >> 16) & 1u);   // RNE
    return (unsigned short)(r >> 16);
}

// ------- pack Z = [incoming|old_h] -> bf16 [B_,KD]  and
//         pack V -> bf16 [ND,KD] with rows interleaved n = 4*h + g ------------
__global__ __launch_bounds__(256) void pack_all(const float* __restrict__ x,
                                                const float* __restrict__ h,
                                                const float* __restrict__ wi, const float* __restrict__ ui,
                                                const float* __restrict__ wo, const float* __restrict__ uo,
                                                const float* __restrict__ wf, const float* __restrict__ uf,
                                                const float* __restrict__ wc, const float* __restrict__ uc,
                                                unsigned short* __restrict__ Z,
                                                unsigned short* __restrict__ V) {
    const int bid = blockIdx.x;
    const float* src;
    unsigned short* dst;
    if (bid < 8192) {
        int idx = (bid * 256 + threadIdx.x) * 4;
        int m = idx >> 11;
        int k = idx & (KD - 1);
        src = (k < IN_) ? (x + (size_t)m * IN_ + k)
                        : (h + (size_t)m * H_ + (k - IN_));
        dst = Z + idx;
    } else {
        int idx = ((bid - 8192) * 256 + threadIdx.x) * 4;
        int n = idx >> 11;          // interleaved row
        int k = idx & (KD - 1);
        int g = n & 3;              // gate 0..3 = i,o,f,c
        int r = n >> 2;             // h index
        const float* wg = (g == 0) ? wi : (g == 1) ? wo : (g == 2) ? wf : wc;
        const float* ug = (g == 0) ? ui : (g == 1) ? uo : (g == 2) ? uf : uc;
        src = (k < IN_) ? (wg + (size_t)r * IN_ + k)
                        : (ug + (size_t)r * H_ + (k - IN_));
        dst = V + idx;
    }
    float4 v = *(const float4*)src;
    ushort4 o;
    o.x = f2bf(v.x); o.y = f2bf(v.y); o.z = f2bf(v.z); o.w = f2bf(v.w);
    *(ushort4*)dst = o;
}

// ---------------------------------------------------------------------------
// 256x256 tile, BK=64, 8 waves (2M x 4N), 8-phase counted-vmcnt schedule
// (T2 XOR-swizzle + T3/T4 counted vmcnt + T5 setprio).  LDS = 128 KiB:
//   buf b: A tile [256][64] bf16 at byte b*65536, B tile at b*65536+32768.
// Staging chunk = 64 rows = 8 KiB = one global_load_lds (512 thr x 16 B).
// Per K-tile t, phases p=0..3 compute quadrant (mi-half=p>>1, ni-half=p&1);
// tile t+1's chunks issued 2/phase: p0:B0B1 p1:B2B3 p2:A0A2 p3:A1A3.
// Waits: vmcnt(4) end of p1 (covers A1,A3 of t, issued 4 loads ago);
//        vmcnt(2) end of p3 (covers B*,A0,A2 of t+1; leaves its A1,A3).
// Raw s_barrier (no compiler vmcnt(0) drain).  LDS swizzle: col-chunk cb of
// row r at slot (cb ^ (r&7)); staged by pre-swizzling the global source col
// (linear LDS dest, m173 pattern).  Verified 0 bank conflicts at 128^2.
// ---------------------------------------------------------------------------
#define AS1 __attribute__((address_space(1)))
#define AS3 __attribute__((address_space(3)))

#define STG(SRC, DST)                                                        \
    __builtin_amdgcn_global_load_lds((const AS1 void*)(SRC),                 \
                                     (AS3 void*)(DST), 16, 0, 0);

#define GPHASE(H, Q, STAGES, VMW)                                            \
  {                                                                          \
    bf16x8 afr[4][2], bfr[2][2];                                             \
    _Pragma("unroll") for (int mi = 0; mi < 4; ++mi)                         \
      _Pragma("unroll") for (int ks = 0; ks < 2; ++ks)                       \
        afr[mi][ks] = *(const bf16x8*)(lA +                                  \
            (wr * 128 + (H) * 64 + mi * 16 + lm) * 64 +                      \
            (((ks * 4 + l4) ^ lm7) * 8));                                    \
    _Pragma("unroll") for (int ni = 0; ni < 2; ++ni)                         \
      _Pragma("unroll") for (int ks = 0; ks < 2; ++ks)                       \
        bfr[ni][ks] = *(const bf16x8*)(lB +                                  \
            (wc * 64 + (Q) * 32 + ni * 16 + lm) * 64 +                       \
            (((ks * 4 + l4) ^ lm7) * 8));                                    \
    STAGES                                                                   \
    __builtin_amdgcn_s_barrier();                                            \
    asm volatile("s_waitcnt lgkmcnt(0)" ::: "memory");                       \
    __builtin_amdgcn_s_setprio(1);                                           \
    _Pragma("unroll") for (int mi = 0; mi < 4; ++mi)                         \
      _Pragma("unroll") for (int ni = 0; ni < 2; ++ni)                       \
        _Pragma("unroll") for (int ks = 0; ks < 2; ++ks)                     \
          acc[(H) * 4 + mi][(Q) * 2 + ni] =                                  \
              __builtin_amdgcn_mfma_f32_16x16x32_bf16(                       \
                  afr[mi][ks], bfr[ni][ks],                                  \
                  acc[(H) * 4 + mi][(Q) * 2 + ni], 0, 0, 0);                 \
    __builtin_amdgcn_s_setprio(0);                                           \
    VMW                                                                      \
    __builtin_amdgcn_s_barrier();                                            \
  }

__global__ __launch_bounds__(512, 2) void gemm_lstm(const unsigned short* __restrict__ Z,
                                                    const unsigned short* __restrict__ V,
                                                    const float* __restrict__ oc,
                                                    const float* __restrict__ bi,
                                                    const float* __restrict__ bo,
                                                    const float* __restrict__ bff,
                                                    const float* __restrict__ bc,
                                                    float* __restrict__ nh,
                                                    float* __restrict__ nc) {
    extern __shared__ char smem[];   // 131072 B

    const int tid  = threadIdx.x;
    const int lane = tid & 63;
    const int w    = tid >> 6;      // 0..7
    const int wr   = w >> 2;        // 0..1  (M half)
    const int wc   = w & 3;         // 0..3  (N quarter)
    const int lm   = lane & 15;
    const int l4   = lane >> 4;
    const int lm7  = lm & 7;

    // XCD swizzle: 256 blocks, 32 per XCD, each XCD a 4x8 (bx,by) rectangle.
    const int bid = blockIdx.x;
    const int xcd = bid & 7;
    const int j   = bid >> 3;                 // 0..31
    const int bx  = (xcd & 3) * 4 + (j & 3);  // 0..15
    const int by  = (xcd >> 2) * 8 + (j >> 2);// 0..15
    const int m0  = by * 256;
    const int n0  = bx * 256;

    f32x4 acc[8][4];
#pragma unroll
    for (int i = 0; i < 8; ++i)
#pragma unroll
        for (int jj = 0; jj < 4; ++jj) acc[i][jj] = (f32x4){0.f, 0.f, 0.f, 0.f};

    // staging addresses: thread tid -> chunk row sr = tid>>3, dest slot tid&7,
    // pre-swizzled global col-chunk (tid&7)^(sr&7).  LDS dest is linear
    // (wave-uniform base + lane*16); chunk c adds c*64 rows / c*8192 bytes.
    const int sr  = tid >> 3;                       // 0..63
    const int scw = ((tid & 7) ^ (sr & 7)) * 8;     // swizzled col element
    const unsigned short* gAs = Z + (size_t)(m0 + sr) * KD + scw;
    const unsigned short* gBs = V + (size_t)(n0 + sr) * KD + scw;
    const int wv1024 = w * 1024;

    // ---- prologue: stage tile 0 into buf0; order B0 B1 B2 B3 A0 A2 A1 A3
    {
        char* sd0 = smem + wv1024;
        STG(gBs,          sd0 + 32768)
        STG(gBs + 131072, sd0 + 40960)
        STG(gBs + 262144, sd0 + 49152)
        STG(gBs + 393216, sd0 + 57344)
        STG(gAs,          sd0)
        STG(gAs + 262144, sd0 + 16384)
        STG(gAs + 131072, sd0 + 8192)
        STG(gAs + 393216, sd0 + 24576)
    }
    asm volatile("s_waitcnt vmcnt(2)" ::: "memory");   // B*,A0,A2 landed
    __builtin_amdgcn_s_barrier();

    // ---- main loop: compute tile t, stage tile t+1 (2 chunks/phase)
#pragma unroll 1
    for (int t = 0; t < NT - 1; ++t) {
        const unsigned short* lA = (const unsigned short*)(smem + (t & 1) * 65536);
        const unsigned short* lB = lA + 16384;
        char* sd = smem + (((t & 1) ^ 1) * 65536) + wv1024;
        const int k1 = (t + 1) * 64;

        GPHASE(0, 0,
               STG(gBs + k1,          sd + 32768)
               STG(gBs + 131072 + k1, sd + 40960), )
        GPHASE(0, 1,
               STG(gBs + 262144 + k1, sd + 49152)
               STG(gBs + 393216 + k1, sd + 57344),
               asm volatile("s_waitcnt vmcnt(4)" ::: "memory");)
        GPHASE(1, 0,
               STG(gAs + k1,          sd)
               STG(gAs + 262144 + k1, sd + 16384), )
        GPHASE(1, 1,
               STG(gAs + 131072 + k1, sd + 8192)
               STG(gAs + 393216 + k1, sd + 24576),
               asm volatile("s_waitcnt vmcnt(2)" ::: "memory");)
    }

    // ---- epilogue tile 31 (buf1), no prefetch
    {
        const unsigned short* lA = (const unsigned short*)(smem + 65536);
        const unsigned short* lB = lA + 16384;
        GPHASE(0, 0, , )
        GPHASE(0, 1, , asm volatile("s_waitcnt vmcnt(0)" ::: "memory");)
        GPHASE(1, 0, , )
        GPHASE(1, 1, , )
    }
    __syncthreads();

    // -------- fused LSTM epilogue (LDS-coalesced I/O), scaled to 256x256 ----
    // acc element: row = m0+wr*128+mi*16+4a+v, col = n0+wc*64+ni*16+4b+g,
    // a=lane>>4, b=(lane>>2)&3, g=lane&3; col = 4*h + gate.
    // LDS scalar slot for (row_local, h_local in 0..63):
    //   row*64 + (h ^ ((row&7)<<2))  -> conflict-free scatter/gather,
    //   float4 chunks stay contiguous (XOR value multiple of 4).
    float* scf = (float*)smem;

    const int a  = lane >> 4;
    const int b  = (lane >> 2) & 3;
    const int g  = lane & 3;
    const int rowl0 = wr * 128 + 4 * a + g;   // + mi*16
    const int hl0   = wc * 16;                // + ni*4 + b
    const int h0g   = bx * 64;

    const int rr = tid >> 4;   // 0..31
    const int cc = tid & 15;   // float4 chunk 0..15

    // phase 0: coalesced old_c -> LDS [0, 64 KiB)
#pragma unroll
    for (int p = 0; p < 8; ++p) {
        const int row = p * 32 + rr;
        float4 v = *(const float4*)(oc + (size_t)(m0 + row) * H_ + h0g + 4 * cc);
        *(float4*)(scf + row * 64 + ((4 * cc) ^ ((row & 7) << 2))) = v;
    }
    __syncthreads();

    // phase 1: gather gates via XOR-shuffle, compute; results stay in regs
    float hv[4][8], cv[4][8];
#pragma unroll
    for (int ni = 0; ni < 4; ++ni) {
        const int hl = hl0 + ni * 4 + b;
        const int hg = h0g + hl;
        const float vbi = bi[hg];
        const float vbo = bo[hg];
        const float vbf = bff[hg];
        const float vbc = bc[hg];
#pragma unroll
        for (int mi = 0; mi < 8; ++mi) {
            const int rowl = rowl0 + mi * 16;
            const float ocv = scf[rowl * 64 + (hl ^ ((rowl & 7) << 2))];
            float recv[4];
#pragma unroll
            for (int t = 0; t < 4; ++t) {
                float xg = acc[mi][ni][(g ^ t) & 3];
                recv[t] = __shfl_xor(xg, t, 64);
            }
            float gi = recv[g] + vbi;
            float go = recv[g ^ 1] + vbo;
            float gf = recv[g ^ 2] + vbf;
            float gc = recv[g ^ 3] + vbc;
            float iv = 1.f / (1.f + __expf(-gi));
            float ov = 1.f / (1.f + __expf(-go));
            float fv = 1.f / (1.f + __expf(-gf));
            float ct = 1.f - 2.f / (__expf(2.f * gc) + 1.f);
            float c2 = fv * ocv + iv * ct;
            float th = 1.f - 2.f / (__expf(2.f * c2) + 1.f);
            cv[ni][mi] = c2;
            hv[ni][mi] = ov * th;
        }
    }
    __syncthreads();   // all old_c reads done before overwrite

    // phase 2: scatter results: nc -> [0,64K), nh -> [64K,128K)
#pragma unroll
    for (int ni = 0; ni < 4; ++ni)
#pragma unroll
        for (int mi = 0; mi < 8; ++mi) {
            const int rowl = rowl0 + mi * 16;
            const int hl = hl0 + ni * 4 + b;
            const int s = rowl * 64 + (hl ^ ((rowl & 7) << 2));
            scf[s] = cv[ni][mi];
            scf[16384 + s] = hv[ni][mi];
        }
    __syncthreads();

    // phase 3: coalesced global stores
#pragma unroll
    for (int p = 0; p < 8; ++p) {
        const int row = p * 32 + rr;
        const int s = row * 64 + ((4 * cc) ^ ((row & 7) << 2));
        float4 vcn = *(const float4*)(scf + s);
        float4 vhn = *(const float4*)(scf + 16384 + s);
        const size_t go_ = (size_t)(m0 + row) * H_ + h0g + 4 * cc;
        *(float4*)(nc + go_) = vcn;
        *(float4*)(nh + go_) = vhn;
    }
}

extern "C" void kernel_launch(void* const* d_in, const int* in_sizes, int n_in,
                              void* d_out, int out_size, void* d_ws, size_t ws_size,
                              hipStream_t stream) {
    const float* incoming = (const float*)d_in[0];
    const float* old_h    = (const float*)d_in[1];
    const float* old_c    = (const float*)d_in[2];
    const float* w_i = (const float*)d_in[3];
    const float* b_i = (const float*)d_in[4];
    const float* u_i = (const float*)d_in[5];
    const float* w_o = (const float*)d_in[6];
    const float* b_o = (const float*)d_in[7];
    const float* u_o = (const float*)d_in[8];
    const float* w_f = (const float*)d_in[9];
    const float* b_f = (const float*)d_in[10];
    const float* u_f = (const float*)d_in[11];
    const float* w_c = (const float*)d_in[12];
    const float* b_c = (const float*)d_in[13];
    const float* u_c = (const float*)d_in[14];

    unsigned short* Z = (unsigned short*)d_ws;                 // 16 MiB
    unsigned short* V = Z + (size_t)B_ * KD;                   // 16 MiB

    static int smem_set = 0;
    if (!smem_set) {
        (void)hipFuncSetAttribute((const void*)gemm_lstm,
                                  hipFuncAttributeMaxDynamicSharedMemorySize,
                                  131072);
        smem_set = 1;
    }

    pack_all<<<16384, 256, 0, stream>>>(incoming, old_h,
                                        w_i, u_i, w_o, u_o, w_f, u_f, w_c, u_c,
                                        Z, V);
    gemm_lstm<<<256, 512, 131072, stream>>>(
        Z, V, old_c, b_i, b_o, b_f, b_c,
        (float*)d_out, (float*)d_out + (size_t)B_ * H_);
}

// Round 2
// 208.151 us; speedup vs baseline: 1.0407x; 1.0407x over previous
//
#include <hip/hip_runtime.h>

typedef __bf16 bf16x8 __attribute__((ext_vector_type(8)));
typedef float f32x4 __attribute__((ext_vector_type(4)));

#define B_  4096   // batch
#define IN_ 1024
#define H_  1024
#define KD  2048   // IN_ + H_
#define ND  4096   // 4 * H_ (gates interleaved: row n = 4*h + g)
#define NT  32     // K tiles of 64

__device__ __forceinline__ unsigned short f2bf(float f) {
    union { float f; unsigned u; } v; v.f = f;
    unsigned r = v.u + 0x7FFFu + ((v.u >> 16) & 1u);   // RNE
    return (unsigned short)(r >> 16);
}

// ------- pack Z = [incoming|old_h] -> bf16 [B_,KD]  and
//         pack V -> bf16 [ND,KD] with rows interleaved n = 4*h + g ------------
__global__ __launch_bounds__(256) void pack_all(const float* __restrict__ x,
                                                const float* __restrict__ h,
                                                const float* __restrict__ wi, const float* __restrict__ ui,
                                                const float* __restrict__ wo, const float* __restrict__ uo,
                                                const float* __restrict__ wf, const float* __restrict__ uf,
                                                const float* __restrict__ wc, const float* __restrict__ uc,
                                                unsigned short* __restrict__ Z,
                                                unsigned short* __restrict__ V) {
    const int bid = blockIdx.x;
    const float* src;
    unsigned short* dst;
    if (bid < 8192) {
        int idx = (bid * 256 + threadIdx.x) * 4;
        int m = idx >> 11;
        int k = idx & (KD - 1);
        src = (k < IN_) ? (x + (size_t)m * IN_ + k)
                        : (h + (size_t)m * H_ + (k - IN_));
        dst = Z + idx;
    } else {
        int idx = ((bid - 8192) * 256 + threadIdx.x) * 4;
        int n = idx >> 11;          // interleaved row
        int k = idx & (KD - 1);
        int g = n & 3;              // gate 0..3 = i,o,f,c
        int r = n >> 2;             // h index
        const float* wg = (g == 0) ? wi : (g == 1) ? wo : (g == 2) ? wf : wc;
        const float* ug = (g == 0) ? ui : (g == 1) ? uo : (g == 2) ? uf : uc;
        src = (k < IN_) ? (wg + (size_t)r * IN_ + k)
                        : (ug + (size_t)r * H_ + (k - IN_));
        dst = V + idx;
    }
    float4 v = *(const float4*)src;
    ushort4 o;
    o.x = f2bf(v.x); o.y = f2bf(v.y); o.z = f2bf(v.z); o.w = f2bf(v.w);
    *(ushort4*)dst = o;
}

// ---------------------------------------------------------------------------
// 256x256 tile, BK=64, 8 waves (2M x 4N), 4-phase/K-tile counted-vmcnt
// schedule with MINIMAL fragment reads (the round-1 regression was 2x
// redundant ds_reads: 48/wave/tile -> 24 here):
//   P0 (H0,Q0): read A-H0 (8) + B-Q0 (4)  [12 reads, lgkmcnt(8) throttle]
//   P1 (H0,Q1): read B-Q1 (4), reuse af
//   P2 (H1,Q1): read A-H1 (8), reuse bf1
//   P3 (H1,Q0): no reads (reuse af, held bf0)
// Staging for tile t+1 interleaved 2 chunks/phase: B0B1|B2B3|A0,A2|A1,A3.
// Waits: vmcnt(4) at P1 end (A1,A3 of tile t, issued a full tile earlier);
//        vmcnt(2) at P3 end (B*,A0,A2 of t+1 landed; its A1,A3 in flight).
// Final tile: vmcnt(0) at P1 end (no prefetch outstanding -> must drain).
// LDS 128 KiB: buf b at b*65536 (A [256][64] bf16; B at +32768).
// XOR swizzle: col-chunk cb of row r at slot (cb ^ (r&7)); staged via
// pre-swizzled global source col, linear LDS dest (verified 0 conflicts).
// ---------------------------------------------------------------------------
#define AS1 __attribute__((address_space(1)))
#define AS3 __attribute__((address_space(3)))

#define STG(SRC, DST)                                                        \
    __builtin_amdgcn_global_load_lds((const AS1 void*)(SRC),                 \
                                     (AS3 void*)(DST), 16, 0, 0);

#define RD_A(H)                                                              \
    _Pragma("unroll") for (int mi = 0; mi < 4; ++mi)                         \
      _Pragma("unroll") for (int ks = 0; ks < 2; ++ks)                       \
        af[mi][ks] = *(const bf16x8*)(lA +                                   \
            (wr * 128 + (H) * 64 + mi * 16 + lm) * 64 +                      \
            (((ks * 4 + l4) ^ lm7) * 8));

#define RD_B(DST, Q)                                                         \
    _Pragma("unroll") for (int ni = 0; ni < 2; ++ni)                         \
      _Pragma("unroll") for (int ks = 0; ks < 2; ++ks)                       \
        DST[ni][ks] = *(const bf16x8*)(lB +                                  \
            (wc * 64 + (Q) * 32 + ni * 16 + lm) * 64 +                       \
            (((ks * 4 + l4) ^ lm7) * 8));

#define MM(H, Q, BF)                                                         \
    __builtin_amdgcn_s_barrier();                                            \
    asm volatile("s_waitcnt lgkmcnt(0)" ::: "memory");                       \
    __builtin_amdgcn_s_setprio(1);                                           \
    _Pragma("unroll") for (int mi = 0; mi < 4; ++mi)                         \
      _Pragma("unroll") for (int ni = 0; ni < 2; ++ni)                       \
        _Pragma("unroll") for (int ks = 0; ks < 2; ++ks)                     \
          acc[(H) * 4 + mi][(Q) * 2 + ni] =                                  \
              __builtin_amdgcn_mfma_f32_16x16x32_bf16(                       \
                  af[mi][ks], BF[ni][ks],                                    \
                  acc[(H) * 4 + mi][(Q) * 2 + ni], 0, 0, 0);                 \
    __builtin_amdgcn_s_setprio(0);

__global__ __launch_bounds__(512, 2) void gemm_lstm(const unsigned short* __restrict__ Z,
                                                    const unsigned short* __restrict__ V,
                                                    const float* __restrict__ oc,
                                                    const float* __restrict__ bi,
                                                    const float* __restrict__ bo,
                                                    const float* __restrict__ bff,
                                                    const float* __restrict__ bc,
                                                    float* __restrict__ nh,
                                                    float* __restrict__ nc) {
    extern __shared__ char smem[];   // 131072 B

    const int tid  = threadIdx.x;
    const int lane = tid & 63;
    const int w    = tid >> 6;      // 0..7
    const int wr   = w >> 2;        // 0..1  (M half)
    const int wc   = w & 3;         // 0..3  (N quarter)
    const int lm   = lane & 15;
    const int l4   = lane >> 4;
    const int lm7  = lm & 7;

    // XCD swizzle: 256 blocks, 32 per XCD, each XCD a 4x8 (bx,by) rectangle.
    const int bid = blockIdx.x;
    const int xcd = bid & 7;
    const int j   = bid >> 3;                 // 0..31
    const int bx  = (xcd & 3) * 4 + (j & 3);  // 0..15
    const int by  = (xcd >> 2) * 8 + (j >> 2);// 0..15
    const int m0  = by * 256;
    const int n0  = bx * 256;

    f32x4 acc[8][4];
#pragma unroll
    for (int i = 0; i < 8; ++i)
#pragma unroll
        for (int jj = 0; jj < 4; ++jj) acc[i][jj] = (f32x4){0.f, 0.f, 0.f, 0.f};

    // staging: thread tid -> chunk row sr = tid>>3, dest slot tid&7,
    // pre-swizzled global col-chunk (tid&7)^(sr&7).  LDS dest linear
    // (wave-uniform base + lane*16); chunk c adds c*64 rows (c*131072 elems
    // global, c*8192 bytes LDS).
    const int sr  = tid >> 3;                       // 0..63
    const int scw = ((tid & 7) ^ (sr & 7)) * 8;     // swizzled col element
    const unsigned short* gAs = Z + (size_t)(m0 + sr) * KD + scw;
    const unsigned short* gBs = V + (size_t)(n0 + sr) * KD + scw;
    const int wv1024 = w * 1024;

    // ---- prologue: stage tile 0 into buf0; order B0 B1 B2 B3 A0 A2 A1 A3
    {
        char* sd0 = smem + wv1024;
        STG(gBs,          sd0 + 32768)
        STG(gBs + 131072, sd0 + 40960)
        STG(gBs + 262144, sd0 + 49152)
        STG(gBs + 393216, sd0 + 57344)
        STG(gAs,          sd0)
        STG(gAs + 262144, sd0 + 16384)
        STG(gAs + 131072, sd0 + 8192)
        STG(gAs + 393216, sd0 + 24576)
    }
    asm volatile("s_waitcnt vmcnt(2)" ::: "memory");   // B*,A0,A2 landed
    __builtin_amdgcn_s_barrier();

    // ---- main loop: compute tile t, stage tile t+1 (2 chunks/phase)
#pragma unroll 1
    for (int t = 0; t < NT - 1; ++t) {
        const unsigned short* lA = (const unsigned short*)(smem + (t & 1) * 65536);
        const unsigned short* lB = lA + 16384;
        char* sd = smem + (((t & 1) ^ 1) * 65536) + wv1024;
        const int k1 = (t + 1) * 64;

        bf16x8 af[4][2], bf0[2][2], bf1[2][2];

        // P0 (H0,Q0): 12 reads + stage B0,B1
        RD_A(0)
        RD_B(bf0, 0)
        STG(gBs + k1,          sd + 32768)
        STG(gBs + 131072 + k1, sd + 40960)
        asm volatile("s_waitcnt lgkmcnt(8)" ::: "memory");
        MM(0, 0, bf0)
        __builtin_amdgcn_s_barrier();

        // P1 (H0,Q1): 4 reads (reuse af) + stage B2,B3
        RD_B(bf1, 1)
        STG(gBs + 262144 + k1, sd + 49152)
        STG(gBs + 393216 + k1, sd + 57344)
        MM(0, 1, bf1)
        asm volatile("s_waitcnt vmcnt(4)" ::: "memory");   // A1,A3 of tile t
        __builtin_amdgcn_s_barrier();

        // P2 (H1,Q1): 8 reads (reuse bf1) + stage A0,A2
        RD_A(1)
        STG(gAs + k1,          sd)
        STG(gAs + 262144 + k1, sd + 16384)
        MM(1, 1, bf1)
        __builtin_amdgcn_s_barrier();

        // P3 (H1,Q0): 0 reads (reuse af, bf0) + stage A1,A3
        STG(gAs + 131072 + k1, sd + 8192)
        STG(gAs + 393216 + k1, sd + 24576)
        MM(1, 0, bf0)
        asm volatile("s_waitcnt vmcnt(2)" ::: "memory");   // B*,A0,A2 of t+1
        __builtin_amdgcn_s_barrier();
    }

    // ---- final tile 31 (buf1), no prefetch
    {
        const unsigned short* lA = (const unsigned short*)(smem + 65536);
        const unsigned short* lB = lA + 16384;
        bf16x8 af[4][2], bf0[2][2], bf1[2][2];

        RD_A(0)
        RD_B(bf0, 0)
        asm volatile("s_waitcnt lgkmcnt(8)" ::: "memory");
        MM(0, 0, bf0)
        __builtin_amdgcn_s_barrier();

        RD_B(bf1, 1)
        MM(0, 1, bf1)
        asm volatile("s_waitcnt vmcnt(0)" ::: "memory");   // drain A1,A3
        __builtin_amdgcn_s_barrier();

        RD_A(1)
        MM(1, 1, bf1)
        __builtin_amdgcn_s_barrier();

        MM(1, 0, bf0)
    }
    __syncthreads();

    // -------- fused LSTM epilogue (LDS-coalesced I/O), 256x256 ----
    // acc element: row = m0+wr*128+mi*16+4a+v, col = n0+wc*64+ni*16+4b+g,
    // a=lane>>4, b=(lane>>2)&3, g=lane&3; col = 4*h + gate.
    // LDS scalar slot for (row_local, h_local in 0..63):
    //   row*64 + (h ^ ((row&7)<<2))  -> conflict-free scatter/gather,
    //   float4 chunks stay contiguous (XOR value multiple of 4).
    float* scf = (float*)smem;

    const int a  = lane >> 4;
    const int b  = (lane >> 2) & 3;
    const int g  = lane & 3;
    const int rowl0 = wr * 128 + 4 * a + g;   // + mi*16
    const int hl0   = wc * 16;                // + ni*4 + b
    const int h0g   = bx * 64;

    const int rr = tid >> 4;   // 0..31
    const int cc = tid & 15;   // float4 chunk 0..15

    // phase 0: coalesced old_c -> LDS [0, 64 KiB)
#pragma unroll
    for (int p = 0; p < 8; ++p) {
        const int row = p * 32 + rr;
        float4 v = *(const float4*)(oc + (size_t)(m0 + row) * H_ + h0g + 4 * cc);
        *(float4*)(scf + row * 64 + ((4 * cc) ^ ((row & 7) << 2))) = v;
    }
    __syncthreads();

    // phase 1: gather gates via XOR-shuffle, compute; results stay in regs
    float hv[4][8], cv[4][8];
#pragma unroll
    for (int ni = 0; ni < 4; ++ni) {
        const int hl = hl0 + ni * 4 + b;
        const int hg = h0g + hl;
        const float vbi = bi[hg];
        const float vbo = bo[hg];
        const float vbf = bff[hg];
        const float vbc = bc[hg];
#pragma unroll
        for (int mi = 0; mi < 8; ++mi) {
            const int rowl = rowl0 + mi * 16;
            const float ocv = scf[rowl * 64 + (hl ^ ((rowl & 7) << 2))];
            float recv[4];
#pragma unroll
            for (int t = 0; t < 4; ++t) {
                float xg = acc[mi][ni][(g ^ t) & 3];
                recv[t] = __shfl_xor(xg, t, 64);
            }
            float gi = recv[g] + vbi;
            float go = recv[g ^ 1] + vbo;
            float gf = recv[g ^ 2] + vbf;
            float gc = recv[g ^ 3] + vbc;
            float iv = 1.f / (1.f + __expf(-gi));
            float ov = 1.f / (1.f + __expf(-go));
            float fv = 1.f / (1.f + __expf(-gf));
            float ct = 1.f - 2.f / (__expf(2.f * gc) + 1.f);
            float c2 = fv * ocv + iv * ct;
            float th = 1.f - 2.f / (__expf(2.f * c2) + 1.f);
            cv[ni][mi] = c2;
            hv[ni][mi] = ov * th;
        }
    }
    __syncthreads();   // all old_c reads done before overwrite

    // phase 2: scatter results: nc -> [0,64K), nh -> [64K,128K)
#pragma unroll
    for (int ni = 0; ni < 4; ++ni)
#pragma unroll
        for (int mi = 0; mi < 8; ++mi) {
            const int rowl = rowl0 + mi * 16;
            const int hl = hl0 + ni * 4 + b;
            const int s = rowl * 64 + (hl ^ ((rowl & 7) << 2));
            scf[s] = cv[ni][mi];
            scf[16384 + s] = hv[ni][mi];
        }
    __syncthreads();

    // phase 3: coalesced global stores
#pragma unroll
    for (int p = 0; p < 8; ++p) {
        const int row = p * 32 + rr;
        const int s = row * 64 + ((4 * cc) ^ ((row & 7) << 2));
        float4 vcn = *(const float4*)(scf + s);
        float4 vhn = *(const float4*)(scf + 16384 + s);
        const size_t go_ = (size_t)(m0 + row) * H_ + h0g + 4 * cc;
        *(float4*)(nc + go_) = vcn;
        *(float4*)(nh + go_) = vhn;
    }
}

extern "C" void kernel_launch(void* const* d_in, const int* in_sizes, int n_in,
                              void* d_out, int out_size, void* d_ws, size_t ws_size,
                              hipStream_t stream) {
    const float* incoming = (const float*)d_in[0];
    const float* old_h    = (const float*)d_in[1];
    const float* old_c    = (const float*)d_in[2];
    const float* w_i = (const float*)d_in[3];
    const float* b_i = (const float*)d_in[4];
    const float* u_i = (const float*)d_in[5];
    const float* w_o = (const float*)d_in[6];
    const float* b_o = (const float*)d_in[7];
    const float* u_o = (const float*)d_in[8];
    const float* w_f = (const float*)d_in[9];
    const float* b_f = (const float*)d_in[10];
    const float* u_f = (const float*)d_in[11];
    const float* w_c = (const float*)d_in[12];
    const float* b_c = (const float*)d_in[13];
    const float* u_c = (const float*)d_in[14];

    unsigned short* Z = (unsigned short*)d_ws;                 // 16 MiB
    unsigned short* V = Z + (size_t)B_ * KD;                   // 16 MiB

    static int smem_set = 0;
    if (!smem_set) {
        (void)hipFuncSetAttribute((const void*)gemm_lstm,
                                  hipFuncAttributeMaxDynamicSharedMemorySize,
                                  131072);
        smem_set = 1;
    }

    pack_all<<<16384, 256, 0, stream>>>(incoming, old_h,
                                        w_i, u_i, w_o, u_o, w_f, u_f, w_c, u_c,
                                        Z, V);
    gemm_lstm<<<256, 512, 131072, stream>>>(
        Z, V, old_c, b_i, b_o, b_f, b_c,
        (float*)d_out, (float*)d_out + (size_t)B_ * H_);
}